// Round 12
// baseline (500.239 us; speedup 1.0000x reference)
//
#include <hip/hip_runtime.h>
#include <hip/hip_bf16.h>
#include <math.h>

#define D_MODEL 768
#define D_STATE 16
#define D_CONVW 4
#define D_INNER 1536
#define BATCH   2
#define SEQLEN  4096
#define NROWS   (BATCH*SEQLEN)       // 8192
#define NCHUNK  128                  // scan TLP: 1536 blocks for phases A/C
#define LCHUNK  (SEQLEN/NCHUNK)      // 32

typedef __attribute__((ext_vector_type(8))) short short8;
typedef __attribute__((ext_vector_type(4))) float floatx4;

__device__ inline unsigned short f2b(float x) {
    unsigned u = __float_as_uint(x);
    return (unsigned short)((u + 0x7fffu + ((u >> 16) & 1u)) >> 16);   // RNE
}
__device__ inline float b2f(unsigned short b) {
    return __uint_as_float(((unsigned)b) << 16);
}

#define GLDS(gp, lp) __builtin_amdgcn_global_load_lds( \
    (const __attribute__((address_space(1))) void*)(gp), \
    (__attribute__((address_space(3))) void*)(lp), 16, 0, 0)

// ---------------------------------------------------------------------------
// 128x128 bf16 MFMA GEMM — ONE barrier per K-tile (r12).
// 3 distinct LDS buffers, prefetch distance 1:
//   STEP(t): stage(t+1) -> vmcnt(4) -> s_barrier -> compute(t)
// Safety: barrier/STEP bounds skew to 1 interval; fast wave's stage(t+2)
// writes buf[(t+2)%3] vs laggard's compute buf[t%3] — distinct (2 mod 3).
// Own vmcnt(4) (4 GLDS in flight = tile t+1) + barrier => tile t complete
// for all waves.  48 KiB LDS -> 3 blocks/CU (unchanged vs r11).
// Granule XOR-swizzle (conflict-free) + L2-aware XCD mapping kept.
// EPI: 0 plain (OUTBF16 sel), 3 fused xp+delta: gn<32 -> f32 C2;
//      32<=gn<N -> softplus(acc+bias[gn-32]) -> BF16 Cv[gm*1536+gn-32]
// NT=K/32 must be divisible by 3 (K=768:24, K=1536:48 ok).
// ---------------------------------------------------------------------------
template<int EPI, int OUTBF16>
__global__ __launch_bounds__(256, 4) void gemm_1b(
    const unsigned short* __restrict__ A, int lda,
    const unsigned short* __restrict__ Bt, int ldb,
    void* __restrict__ Cv, int ldc, float* __restrict__ C2,
    int N, int K, const float* __restrict__ bias, int nbx)
{
    __shared__ unsigned short As0[128*32], As1[128*32], As2[128*32];
    __shared__ unsigned short Bs0[128*32], Bs1[128*32], Bs2[128*32];

    // XCD-aware mapping: round-robin xcd = wg&7; within an XCD walk
    // (R bm-rows x 2 bn-cols) super-tiles -> ~3.9MB L2 working set.
    const int nwg = gridDim.x;
    const int cpx = nwg >> 3;
    const int wg  = blockIdx.x;
    const int xcd = wg & 7, local = wg >> 3;
    int bmi, bni;
    if ((cpx % nbx == 0) && ((nbx & 1) == 0)) {
        const int R   = cpx / nbx;
        const int p   = local / (2 * R);
        const int idx = local % (2 * R);
        bmi = xcd * R + (idx >> 1);
        bni = p * 2 + (idx & 1);
    } else {
        const int swz = xcd * cpx + local;
        bmi = swz / nbx;
        bni = swz % nbx;
    }
    const int bm = bmi * 128;
    const int bn = bni * 128;

    const int tid  = threadIdx.x;
    const int lane = tid & 63;
    const int wave = tid >> 6;
    const int wm   = (wave >> 1) * 64;
    const int wn   = (wave & 1) * 64;
    const int l15  = lane & 15;
    const int lg   = lane >> 4;

    const int sr    = tid >> 2;                              // source row (+p*64)
    const int sg    = ((tid & 3) ^ ((tid >> 3) & 3)) * 8;    // swizzled src granule
    const int lbase = (tid & ~63) * 16;                      // wave-uniform LDS base

    floatx4 acc[4][4] = {};

    auto stagePair = [&](unsigned short (&SA)[128*32],
                         unsigned short (&SB)[128*32], int kt) {
        #pragma unroll
        for (int p = 0; p < 2; ++p) {
            const unsigned short* ga = A + (size_t)(bm + p * 64 + sr) * lda + kt + sg;
            GLDS(ga, (char*)SA + p * 4096 + lbase);
        }
        #pragma unroll
        for (int p = 0; p < 2; ++p) {
            const unsigned short* gb = Bt + (size_t)(bn + p * 64 + sr) * ldb + kt + sg;
            GLDS(gb, (char*)SB + p * 4096 + lbase);
        }
    };

    auto compute = [&](const unsigned short (&CA)[128*32],
                       const unsigned short (&CB)[128*32]) {
        short8 af[4], bfv[4];
        #pragma unroll
        for (int i = 0; i < 4; ++i) {
            const int tr = wm + i * 16 + l15;
            const int ge = lg ^ ((tr >> 1) & 3);
            af[i] = *(const short8*)((const char*)CA + tr * 64 + ge * 16);
        }
        #pragma unroll
        for (int j = 0; j < 4; ++j) {
            const int tr = wn + j * 16 + l15;
            const int ge = lg ^ ((tr >> 1) & 3);
            bfv[j] = *(const short8*)((const char*)CB + tr * 64 + ge * 16);
        }
        #pragma unroll
        for (int i = 0; i < 4; ++i)
            #pragma unroll
            for (int j = 0; j < 4; ++j)
                acc[i][j] = __builtin_amdgcn_mfma_f32_16x16x32_bf16(
                    af[i], bfv[j], acc[i][j], 0, 0, 0);
    };

    const int NT = K >> 5;                 // K/32, divisible by 3

    stagePair(As0, Bs0, 0);                // prologue: tile 0 -> buf0

    #define STEP(SA, SB, CA, CB, T)                                          \
    {                                                                        \
        const int t_ = (T);                                                  \
        if (t_ + 1 < NT) {                                                   \
            stagePair(SA, SB, (t_ + 1) * 32);                                \
            asm volatile("s_waitcnt vmcnt(4)" ::: "memory");                 \
        } else {                                                             \
            asm volatile("s_waitcnt vmcnt(0)" ::: "memory");                 \
        }                                                                    \
        __builtin_amdgcn_sched_barrier(0);                                   \
        __builtin_amdgcn_s_barrier();                                        \
        __builtin_amdgcn_sched_barrier(0);                                   \
        compute(CA, CB);                                                     \
    }

    for (int t = 0; t < NT; t += 3) {
        STEP(As1, Bs1, As0, Bs0, t);       // stage t+1 -> buf1, compute t (buf0)
        STEP(As2, Bs2, As1, Bs1, t + 1);   // stage t+2 -> buf2, compute t+1
        STEP(As0, Bs0, As2, Bs2, t + 2);   // stage t+3 -> buf0, compute t+2
    }
    #undef STEP

    // C/D layout: col = lane&15, row = (lane>>4)*4 + reg  (m89-verified)
    #pragma unroll
    for (int i = 0; i < 4; ++i) {
        #pragma unroll
        for (int r = 0; r < 4; ++r) {
            const int gm = bm + wm + i * 16 + lg * 4 + r;
            #pragma unroll
            for (int j = 0; j < 4; ++j) {
                const int gn = bn + wn + j * 16 + l15;
                float v = acc[i][j][r];
                if (EPI == 3) {
                    if (gn < 32) {
                        C2[(size_t)gm * 32 + gn] = v;
                    } else if (gn < N) {
                        v += bias[gn - 32];
                        v = (v > 20.f) ? v : log1pf(__expf(v));
                        ((unsigned short*)Cv)[(size_t)gm * 1536 + gn - 32] = f2b(v);
                    }
                } else {
                    if (gn < N) {
                        if (OUTBF16)
                            ((unsigned short*)Cv)[(size_t)gm * ldc + gn] = f2b(v);
                        else
                            ((float*)Cv)[(size_t)gm * ldc + gn] = v;
                    }
                }
            }
        }
    }
}

// ---------------------------------------------------------------------------
// W[K][N] f32 -> Wt[N_pad][K] bf16 (pad rows zeroed).  32x32 LDS transpose.
// ---------------------------------------------------------------------------
__global__ __launch_bounds__(256) void transpose_bf16(
    const float* __restrict__ W, unsigned short* __restrict__ Wt, int K, int N)
{
    __shared__ float t[32][33];
    const int nt = blockIdx.x * 32, kt = blockIdx.y * 32;
    const int tx = threadIdx.x & 31, ty = threadIdx.x >> 5;
    #pragma unroll
    for (int r = 0; r < 4; ++r) {
        const int k = ty + r * 8;
        const int n = nt + tx;
        float v = 0.f;
        if (n < N) v = W[(size_t)(kt + k) * N + n];
        t[k][tx] = v;
    }
    __syncthreads();
    #pragma unroll
    for (int r = 0; r < 4; ++r) {
        const int nl = ty + r * 8;
        Wt[(size_t)(nt + nl) * K + kt + tx] = f2b(t[tx][nl]);
    }
}

__global__ __launch_bounds__(256) void f32_to_bf16(
    const float* __restrict__ in, unsigned short* __restrict__ o, int n4)
{
    const int i = blockIdx.x * 256 + threadIdx.x;
    if (i >= n4) return;
    float4 v = ((const float4*)in)[i];
    ushort4 r;
    r.x = f2b(v.x); r.y = f2b(v.y); r.z = f2b(v.z); r.w = f2b(v.w);
    ((ushort4*)o)[i] = r;
}

// W_x[:, 32:] f32 (stride 1568) -> wxb[1536][1536] bf16
__global__ __launch_bounds__(256) void wx32_to_bf16(
    const float* __restrict__ Wx, unsigned short* __restrict__ o)
{
    const int i = blockIdx.x * 256 + threadIdx.x;   // over 1536*384
    if (i >= 1536 * 384) return;
    const int row = i / 384, q = i % 384;
    float4 v = *(const float4*)(Wx + (size_t)row * 1568 + 32 + q * 4);
    ushort4 r;
    r.x = f2b(v.x); r.y = f2b(v.y); r.z = f2b(v.z); r.w = f2b(v.w);
    *(ushort4*)(o + (size_t)row * 1536 + q * 4) = r;
}

// ---------------------------------------------------------------------------
// Depthwise causal conv (width 4) + bias + SiLU, 8 channels/thread, bf16.
// ---------------------------------------------------------------------------
__global__ __launch_bounds__(256) void conv_silu8(
    const unsigned short* __restrict__ xzb, const float* __restrict__ w,
    const float* __restrict__ cb, unsigned short* __restrict__ ub)
{
    const int i = blockIdx.x * 256 + threadIdx.x;    // over NROWS*192
    if (i >= NROWS * 192) return;
    const int g   = i % 192;
    const int row = i / 192;
    const int l   = row % SEQLEN;
    const int d0  = g * 8;

    short8 xr[4];
    #pragma unroll
    for (int k = 0; k < 4; ++k) {
        const int ll = l - 3 + k;
        if (ll >= 0)
            xr[k] = *(const short8*)&xzb[(size_t)(row - 3 + k) * 3072 + d0];
        else
            xr[k] = short8{0,0,0,0,0,0,0,0};
    }
    unsigned short o[8];
    #pragma unroll
    for (int e = 0; e < 8; ++e) {
        float4 we = *(const float4*)&w[(d0 + e) * 4];
        float a = cb[d0 + e];
        a = fmaf(b2f((unsigned short)xr[0][e]), we.x, a);
        a = fmaf(b2f((unsigned short)xr[1][e]), we.y, a);
        a = fmaf(b2f((unsigned short)xr[2][e]), we.z, a);
        a = fmaf(b2f((unsigned short)xr[3][e]), we.w, a);
        o[e] = f2b(a / (1.f + __expf(-a)));
    }
    *(short8*)&ub[(size_t)row * 1536 + d0] = *(short8*)o;
}

// ---------------------------------------------------------------------------
// Per-row softmax over B (16) + copy C (16) from compact xp32[row][32].
// ---------------------------------------------------------------------------
__global__ __launch_bounds__(256) void softmax_bc_kernel(
    const float* __restrict__ xp32, float* __restrict__ Bsm, float* __restrict__ Csm)
{
    const int row = blockIdx.x * 256 + threadIdx.x;
    if (row >= NROWS) return;
    const float* p = xp32 + (size_t)row * 32;
    float v[16];
    #pragma unroll
    for (int q = 0; q < 4; ++q) {
        float4 t = *(const float4*)(p + q * 4);
        v[q*4+0]=t.x; v[q*4+1]=t.y; v[q*4+2]=t.z; v[q*4+3]=t.w;
    }
    float mx = v[0];
    #pragma unroll
    for (int s = 1; s < 16; ++s) mx = fmaxf(mx, v[s]);
    float sum = 0.f;
    #pragma unroll
    for (int s = 0; s < 16; ++s) { v[s] = __expf(v[s] - mx); sum += v[s]; }
    const float inv = 1.f / sum;
    float* bo = Bsm + (size_t)row * 16;
    float* co = Csm + (size_t)row * 16;
    #pragma unroll
    for (int s = 0; s < 16; ++s) bo[s] = v[s] * inv;
    #pragma unroll
    for (int q = 0; q < 4; ++q)
        *(float4*)(co + q * 4) = *(const float4*)(p + 16 + q * 4);
}

// ---------------------------------------------------------------------------
// Scan phase A: per (b, chunk, d): chunk-final state (zero init) + dt-sum.
// delta is bf16 (r12) — A and C read identical values so the chunk
// decomposition identity stays exact.
// ---------------------------------------------------------------------------
__global__ __launch_bounds__(256) void scan_chunk_state(
    const unsigned short* __restrict__ deltab, const unsigned short* __restrict__ ub,
    const float* __restrict__ Bsm, const float* __restrict__ A_log,
    float* __restrict__ chunkS, float* __restrict__ dtsum)
{
    const int gid = blockIdx.x * 256 + threadIdx.x;   // (b*NCHUNK+c)*D_INNER+d
    const int d = gid % D_INNER;
    const int c = (gid / D_INNER) % NCHUNK;
    const int b = gid / (D_INNER * NCHUNK);

    float A2[16];
    #pragma unroll
    for (int q = 0; q < 4; ++q) {
        float4 t = *(const float4*)(A_log + d * 16 + q * 4);
        A2[q*4+0] = -__expf(t.x) * 1.44269504089f;
        A2[q*4+1] = -__expf(t.y) * 1.44269504089f;
        A2[q*4+2] = -__expf(t.z) * 1.44269504089f;
        A2[q*4+3] = -__expf(t.w) * 1.44269504089f;
    }
    float h[16];
    #pragma unroll
    for (int s = 0; s < 16; ++s) h[s] = 0.f;
    float dts = 0.f;

    const int t0 = c * LCHUNK;
    for (int t = t0; t < t0 + LCHUNK; ++t) {
        const size_t rowoff = (size_t)b * SEQLEN + t;
        const float dt = b2f(deltab[rowoff * D_INNER + d]);
        const float uu = b2f(ub[rowoff * D_INNER + d]);
        const float du = dt * uu;
        dts += dt;
        const float4* Bp = (const float4*)(Bsm + rowoff * 16);
        float Bv[16];
        #pragma unroll
        for (int q = 0; q < 4; ++q) {
            float4 tb = Bp[q];
            Bv[q*4+0]=tb.x; Bv[q*4+1]=tb.y; Bv[q*4+2]=tb.z; Bv[q*4+3]=tb.w;
        }
        #pragma unroll
        for (int s = 0; s < 16; ++s) {
            const float dA = exp2f(dt * A2[s]);
            h[s] = fmaf(dA, h[s], du * Bv[s]);
        }
    }
    float* S = chunkS + (size_t)gid * 16;
    #pragma unroll
    for (int q = 0; q < 4; ++q)
        *(float4*)(S + q * 4) = make_float4(h[q*4+0], h[q*4+1], h[q*4+2], h[q*4+3]);
    dtsum[gid] = dts;
}

// ---------------------------------------------------------------------------
// Scan phase B: inter-chunk scan; chunkS becomes chunk-INITIAL states.
// ---------------------------------------------------------------------------
__global__ __launch_bounds__(256) void scan_chunk_scan(
    const float* __restrict__ A_log, const float* __restrict__ dtsum,
    float* __restrict__ chunkS)
{
    const int gid = blockIdx.x * 256 + threadIdx.x;   // (b*D_INNER+d)*16+s
    if (gid >= BATCH * D_INNER * 16) return;
    const int s = gid % 16;
    const int d = (gid / 16) % D_INNER;
    const int b = gid / (16 * D_INNER);
    const float A2 = -__expf(A_log[d * 16 + s]) * 1.44269504089f;
    float hprev = 0.f;
    for (int c = 0; c < NCHUNK; ++c) {
        const size_t cidx = ((size_t)(b * NCHUNK + c) * D_INNER + d);
        const float P  = exp2f(A2 * dtsum[cidx]);
        const size_t idx = cidx * 16 + s;
        const float Sc = chunkS[idx];
        chunkS[idx] = hprev;
        hprev = fmaf(P, hprev, Sc);
    }
}

// ---------------------------------------------------------------------------
// Scan phase C: re-run chunks from initial states, y = (C.h) * silu(z), bf16.
// ---------------------------------------------------------------------------
__global__ __launch_bounds__(256) void scan_output(
    const unsigned short* __restrict__ deltab, const unsigned short* __restrict__ ub,
    const float* __restrict__ Bsm, const float* __restrict__ Csm,
    const float* __restrict__ A_log, const float* __restrict__ chunkS,
    const unsigned short* __restrict__ xzb, unsigned short* __restrict__ yb)
{
    const int gid = blockIdx.x * 256 + threadIdx.x;
    const int d = gid % D_INNER;
    const int c = (gid / D_INNER) % NCHUNK;
    const int b = gid / (D_INNER * NCHUNK);

    float A2[16];
    #pragma unroll
    for (int q = 0; q < 4; ++q) {
        float4 t = *(const float4*)(A_log + d * 16 + q * 4);
        A2[q*4+0] = -__expf(t.x) * 1.44269504089f;
        A2[q*4+1] = -__expf(t.y) * 1.44269504089f;
        A2[q*4+2] = -__expf(t.z) * 1.44269504089f;
        A2[q*4+3] = -__expf(t.w) * 1.44269504089f;
    }
    float h[16];
    const float* S = chunkS + (size_t)gid * 16;
    #pragma unroll
    for (int q = 0; q < 4; ++q) {
        float4 t = *(const float4*)(S + q * 4);
        h[q*4+0]=t.x; h[q*4+1]=t.y; h[q*4+2]=t.z; h[q*4+3]=t.w;
    }

    const int t0 = c * LCHUNK;
    for (int t = t0; t < t0 + LCHUNK; ++t) {
        const size_t rowoff = (size_t)b * SEQLEN + t;
        const float dt = b2f(deltab[rowoff * D_INNER + d]);
        const float uu = b2f(ub[rowoff * D_INNER + d]);
        const float du = dt * uu;
        const float4* Bp = (const float4*)(Bsm + rowoff * 16);
        const float4* Cp = (const float4*)(Csm + rowoff * 16);
        float Bv[16], Cv[16];
        #pragma unroll
        for (int q = 0; q < 4; ++q) {
            float4 tb = Bp[q], tc = Cp[q];
            Bv[q*4+0]=tb.x; Bv[q*4+1]=tb.y; Bv[q*4+2]=tb.z; Bv[q*4+3]=tb.w;
            Cv[q*4+0]=tc.x; Cv[q*4+1]=tc.y; Cv[q*4+2]=tc.z; Cv[q*4+3]=tc.w;
        }
        float yv = 0.f;
        #pragma unroll
        for (int s = 0; s < 16; ++s) {
            const float dA = exp2f(dt * A2[s]);
            h[s] = fmaf(dA, h[s], du * Bv[s]);
            yv = fmaf(Cv[s], h[s], yv);
        }
        const float z = b2f(xzb[rowoff * (2 * D_INNER) + D_INNER + d]);
        const float sz = z / (1.f + __expf(-z));
        yb[rowoff * D_INNER + d] = f2b(yv * sz);
    }
}

// ---------------------------------------------------------------------------
extern "C" void kernel_launch(void* const* d_in, const int* in_sizes, int n_in,
                              void* d_out, int out_size, void* d_ws, size_t ws_size,
                              hipStream_t stream)
{
    const float* hs     = (const float*)d_in[0];
    const float* W_in   = (const float*)d_in[1];
    const float* conv_w = (const float*)d_in[2];
    const float* conv_b = (const float*)d_in[3];
    const float* W_x    = (const float*)d_in[4];
    const float* W_dt   = (const float*)d_in[5];
    const float* b_dt   = (const float*)d_in[6];
    const float* A_log  = (const float*)d_in[7];
    const float* W_out  = (const float*)d_in[9];
    float* out = (float*)d_out;

    // workspace layout (256B aligned)
    char* w = (char*)d_ws;
    auto alloc = [&](size_t bytes) { char* p = w; w += (bytes + 255) & ~(size_t)255; return p; };
    float*          xp32   = (float*)alloc((size_t)NROWS * 32 * 4);
    unsigned short* deltab = (unsigned short*)alloc((size_t)NROWS * 1536 * 2);
    float*          Bsm    = (float*)alloc((size_t)NROWS * 16 * 4);
    float*          Csm    = (float*)alloc((size_t)NROWS * 16 * 4);
    float*          chunkS = (float*)alloc((size_t)BATCH * NCHUNK * D_INNER * 16 * 4);
    float*          dtsum  = (float*)alloc((size_t)BATCH * NCHUNK * D_INNER * 4);
    unsigned short* xzb    = (unsigned short*)alloc((size_t)NROWS * 3072 * 2);
    unsigned short* ub     = (unsigned short*)alloc((size_t)NROWS * 1536 * 2);
    unsigned short* yb     = (unsigned short*)alloc((size_t)NROWS * 1536 * 2);
    unsigned short* hsb    = (unsigned short*)alloc((size_t)NROWS * 768 * 2);
    unsigned short* Wt_in  = (unsigned short*)alloc((size_t)3072 * 768 * 2);
    unsigned short* Wt_x   = (unsigned short*)alloc((size_t)1792 * 1536 * 2);
    unsigned short* Wt_dt  = (unsigned short*)alloc((size_t)1536 * 1536 * 2);
    unsigned short* Wt_out = (unsigned short*)alloc((size_t)768 * 1536 * 2);
    unsigned short* wxb    = (unsigned short*)alloc((size_t)1536 * 1536 * 2);

    const dim3 blk(256);

    // 0) weight transposes + converts
    transpose_bf16<<<dim3(3072/32, 768/32),  blk, 0, stream>>>(W_in,  Wt_in,  768,  3072);
    transpose_bf16<<<dim3(1792/32, 1536/32), blk, 0, stream>>>(W_x,   Wt_x,   1536, 1568);
    transpose_bf16<<<dim3(1536/32, 1536/32), blk, 0, stream>>>(W_dt,  Wt_dt,  1536, 1536);
    transpose_bf16<<<dim3(768/32,  1536/32), blk, 0, stream>>>(W_out, Wt_out, 1536, 768);
    f32_to_bf16<<<(NROWS*768/4 + 255)/256, blk, 0, stream>>>(hs, hsb, NROWS*768/4);
    wx32_to_bf16<<<(1536*384 + 255)/256, blk, 0, stream>>>(W_x, wxb);

    // 0b) W_comb^T = (W_x[:,32:] @ W_dt)^T spliced into Wt_x rows 32..1567:
    //     [M=1536, N=1536, K=1536; grid 12*12=144, %8==0; fallback mapping]
    gemm_1b<0,1><<<dim3(144), blk, 0, stream>>>(
        Wt_dt, 1536, wxb, 1536, Wt_x + (size_t)32 * 1536, 1536, nullptr,
        1536, 1536, nullptr, 12);

    // 1) xz = hs @ W_in  (bf16 out)  [K=768, NT=24; grid 24*64=1536, %8==0]
    gemm_1b<0,1><<<dim3(1536), blk, 0, stream>>>(
        hsb, 768, Wt_in, 768, xzb, 3072, nullptr, 3072, 768, nullptr, 24);

    // 2) u = silu(conv(x) + cb)
    conv_silu8<<<(NROWS*192)/256, blk, 0, stream>>>(xzb, conv_w, conv_b, ub);

    // 3) fused xp+delta GEMM: u @ [W_x[:,:32] | W_comb]:
    //    cols<32 -> xp32 f32;  cols>=32 -> delta = softplus(acc+b_dt) bf16
    //    [K=1536, NT=48; grid 14*64=896, %8==0]
    gemm_1b<3,0><<<dim3(896), blk, 0, stream>>>(
        ub, 1536, Wt_x, 1536, deltab, 1536, xp32, 1568, 1536, b_dt, 14);

    // 4) Bsm = softmax(xp32[:, :16]), Csm = xp32[:, 16:32]
    softmax_bc_kernel<<<NROWS/256, blk, 0, stream>>>(xp32, Bsm, Csm);

    // 5-7) chunked selective scan (NCHUNK=128: 1536 blocks for A/C)
    scan_chunk_state<<<(BATCH*NCHUNK*D_INNER)/256, blk, 0, stream>>>(
        deltab, ub, Bsm, A_log, chunkS, dtsum);
    scan_chunk_scan<<<(BATCH*D_INNER*16 + 255)/256, blk, 0, stream>>>(
        A_log, dtsum, chunkS);
    scan_output<<<(BATCH*NCHUNK*D_INNER)/256, blk, 0, stream>>>(
        deltab, ub, Bsm, Csm, A_log, chunkS, xzb, yb);

    // 8) out = y @ W_out  (f32 out)  [K=1536, NT=48; grid 6*64=384, %8==0]
    gemm_1b<0,0><<<dim3(384), blk, 0, stream>>>(
        yb, 1536, Wt_out, 1536, out, 768, nullptr, 768, 1536, nullptr, 6);
}

// Round 13
// 442.658 us; speedup vs baseline: 1.1301x; 1.1301x over previous
//
#include <hip/hip_runtime.h>
#include <hip/hip_bf16.h>
#include <math.h>

#define D_MODEL 768
#define D_STATE 16
#define D_CONVW 4
#define D_INNER 1536
#define BATCH   2
#define SEQLEN  4096
#define NROWS   (BATCH*SEQLEN)       // 8192
#define NCHUNK  128                  // scan TLP: 1536 blocks for phases A/C
#define LCHUNK  (SEQLEN/NCHUNK)      // 32

typedef __attribute__((ext_vector_type(8))) short short8;
typedef __attribute__((ext_vector_type(4))) float floatx4;

__device__ inline unsigned short f2b(float x) {
    unsigned u = __float_as_uint(x);
    return (unsigned short)((u + 0x7fffu + ((u >> 16) & 1u)) >> 16);   // RNE
}
__device__ inline float b2f(unsigned short b) {
    return __uint_as_float(((unsigned)b) << 16);
}

#define GLDS(gp, lp) __builtin_amdgcn_global_load_lds( \
    (const __attribute__((address_space(1))) void*)(gp), \
    (__attribute__((address_space(3))) void*)(lp), 16, 0, 0)

// ---------------------------------------------------------------------------
// 128x128 bf16 MFMA GEMM — r11's proven structure (best measured: 117us on
// fused xp): 2-buffer pipeline, TWO barriers per K-tile, 32 KiB LDS,
// __launch_bounds__(256,4) (no spill), granule XOR-swizzle (0 conflicts),
// L2-capacity-aware XCD mapping.  r12's 1-barrier/3-buffer variant REGRESSED
// (183us, occupancy 20%) — do not re-try.
// C[M,N] = A[M,K] @ B[K,N]; B as Bt[N_pad][K].  BK=32, 256 thr = 4 waves,
// wave = 64x64 quadrant (4x4 16x16x32 frags).  NT=K/32 must be even.
// EPI: 0 plain (OUTBF16 sel), 3 fused xp+delta: gn<32 -> f32 C2;
//      32<=gn<N -> softplus(acc+bias[gn-32]) -> BF16 Cv[gm*1536+gn-32]
// Grid 1D = nbx*(M/128), %8==0.
// ---------------------------------------------------------------------------
template<int EPI, int OUTBF16>
__global__ __launch_bounds__(256, 4) void gemm_p2(
    const unsigned short* __restrict__ A, int lda,
    const unsigned short* __restrict__ Bt, int ldb,
    void* __restrict__ Cv, int ldc, float* __restrict__ C2,
    int N, int K, const float* __restrict__ bias, int nbx)
{
    __shared__ unsigned short As0[128*32], As1[128*32];
    __shared__ unsigned short Bs0[128*32], Bs1[128*32];

    // XCD-aware mapping: round-robin xcd = wg&7; within an XCD walk
    // (R bm-rows x 2 bn-cols) super-tiles -> ~3.9MB L2 working set.
    const int nwg = gridDim.x;
    const int cpx = nwg >> 3;
    const int wg  = blockIdx.x;
    const int xcd = wg & 7, local = wg >> 3;
    int bmi, bni;
    if ((cpx % nbx == 0) && ((nbx & 1) == 0)) {
        const int R   = cpx / nbx;
        const int p   = local / (2 * R);
        const int idx = local % (2 * R);
        bmi = xcd * R + (idx >> 1);
        bni = p * 2 + (idx & 1);
    } else {
        const int swz = xcd * cpx + local;
        bmi = swz / nbx;
        bni = swz % nbx;
    }
    const int bm = bmi * 128;
    const int bn = bni * 128;

    const int tid  = threadIdx.x;
    const int lane = tid & 63;
    const int wave = tid >> 6;
    const int wm   = (wave >> 1) * 64;
    const int wn   = (wave & 1) * 64;
    const int l15  = lane & 15;
    const int lg   = lane >> 4;

    const int sr    = tid >> 2;                              // source row (+p*64)
    const int sg    = ((tid & 3) ^ ((tid >> 3) & 3)) * 8;    // swizzled src granule
    const int lbase = (tid & ~63) * 16;                      // wave-uniform LDS base

    floatx4 acc[4][4] = {};

    auto stagePair = [&](unsigned short (&SA)[128*32],
                         unsigned short (&SB)[128*32], int kt) {
        #pragma unroll
        for (int p = 0; p < 2; ++p) {
            const unsigned short* ga = A + (size_t)(bm + p * 64 + sr) * lda + kt + sg;
            GLDS(ga, (char*)SA + p * 4096 + lbase);
        }
        #pragma unroll
        for (int p = 0; p < 2; ++p) {
            const unsigned short* gb = Bt + (size_t)(bn + p * 64 + sr) * ldb + kt + sg;
            GLDS(gb, (char*)SB + p * 4096 + lbase);
        }
    };

    auto compute = [&](const unsigned short (&CA)[128*32],
                       const unsigned short (&CB)[128*32]) {
        short8 af[4], bfv[4];
        #pragma unroll
        for (int i = 0; i < 4; ++i) {
            const int tr = wm + i * 16 + l15;
            const int ge = lg ^ ((tr >> 1) & 3);
            af[i] = *(const short8*)((const char*)CA + tr * 64 + ge * 16);
        }
        #pragma unroll
        for (int j = 0; j < 4; ++j) {
            const int tr = wn + j * 16 + l15;
            const int ge = lg ^ ((tr >> 1) & 3);
            bfv[j] = *(const short8*)((const char*)CB + tr * 64 + ge * 16);
        }
        #pragma unroll
        for (int i = 0; i < 4; ++i)
            #pragma unroll
            for (int j = 0; j < 4; ++j)
                acc[i][j] = __builtin_amdgcn_mfma_f32_16x16x32_bf16(
                    af[i], bfv[j], acc[i][j], 0, 0, 0);
    };

    const int NT = K >> 5;                 // K/32, even

    stagePair(As0, Bs0, 0);                // prologue: tile 0 -> buf0

    #define STEP(SA, SB, CA, CB, T)                                          \
    {                                                                        \
        const int t_ = (T);                                                  \
        if (t_ + 1 < NT) {                                                   \
            stagePair(SA, SB, (t_ + 1) * 32);                                \
            asm volatile("s_waitcnt vmcnt(4)" ::: "memory");                 \
        } else {                                                             \
            asm volatile("s_waitcnt vmcnt(0)" ::: "memory");                 \
        }                                                                    \
        __builtin_amdgcn_sched_barrier(0);                                   \
        __builtin_amdgcn_s_barrier();                                        \
        __builtin_amdgcn_sched_barrier(0);                                   \
        compute(CA, CB);                                                     \
        __builtin_amdgcn_sched_barrier(0);                                   \
        __builtin_amdgcn_s_barrier();                                        \
        __builtin_amdgcn_sched_barrier(0);                                   \
    }

    for (int t = 0; t < NT; t += 2) {
        STEP(As1, Bs1, As0, Bs0, t);       // stage t+1 -> buf1, compute tile t
        STEP(As0, Bs0, As1, Bs1, t + 1);   // stage t+2 -> buf0, compute t+1
    }
    #undef STEP

    // C/D layout: col = lane&15, row = (lane>>4)*4 + reg  (m89-verified)
    #pragma unroll
    for (int i = 0; i < 4; ++i) {
        #pragma unroll
        for (int r = 0; r < 4; ++r) {
            const int gm = bm + wm + i * 16 + lg * 4 + r;
            #pragma unroll
            for (int j = 0; j < 4; ++j) {
                const int gn = bn + wn + j * 16 + l15;
                float v = acc[i][j][r];
                if (EPI == 3) {
                    if (gn < 32) {
                        C2[(size_t)gm * 32 + gn] = v;
                    } else if (gn < N) {
                        v += bias[gn - 32];
                        v = (v > 20.f) ? v : log1pf(__expf(v));
                        ((unsigned short*)Cv)[(size_t)gm * 1536 + gn - 32] = f2b(v);
                    }
                } else {
                    if (gn < N) {
                        if (OUTBF16)
                            ((unsigned short*)Cv)[(size_t)gm * ldc + gn] = f2b(v);
                        else
                            ((float*)Cv)[(size_t)gm * ldc + gn] = v;
                    }
                }
            }
        }
    }
}

// ---------------------------------------------------------------------------
// W[K][N] f32 -> Wt[N_pad][K] bf16 (pad rows zeroed).  32x32 LDS transpose.
// ---------------------------------------------------------------------------
__global__ __launch_bounds__(256) void transpose_bf16(
    const float* __restrict__ W, unsigned short* __restrict__ Wt, int K, int N)
{
    __shared__ float t[32][33];
    const int nt = blockIdx.x * 32, kt = blockIdx.y * 32;
    const int tx = threadIdx.x & 31, ty = threadIdx.x >> 5;
    #pragma unroll
    for (int r = 0; r < 4; ++r) {
        const int k = ty + r * 8;
        const int n = nt + tx;
        float v = 0.f;
        if (n < N) v = W[(size_t)(kt + k) * N + n];
        t[k][tx] = v;
    }
    __syncthreads();
    #pragma unroll
    for (int r = 0; r < 4; ++r) {
        const int nl = ty + r * 8;
        Wt[(size_t)(nt + nl) * K + kt + tx] = f2b(t[tx][nl]);
    }
}

__global__ __launch_bounds__(256) void f32_to_bf16(
    const float* __restrict__ in, unsigned short* __restrict__ o, int n4)
{
    const int i = blockIdx.x * 256 + threadIdx.x;
    if (i >= n4) return;
    float4 v = ((const float4*)in)[i];
    ushort4 r;
    r.x = f2b(v.x); r.y = f2b(v.y); r.z = f2b(v.z); r.w = f2b(v.w);
    ((ushort4*)o)[i] = r;
}

// W_x[:, 32:] f32 (stride 1568) -> wxb[1536][1536] bf16
__global__ __launch_bounds__(256) void wx32_to_bf16(
    const float* __restrict__ Wx, unsigned short* __restrict__ o)
{
    const int i = blockIdx.x * 256 + threadIdx.x;   // over 1536*384
    if (i >= 1536 * 384) return;
    const int row = i / 384, q = i % 384;
    float4 v = *(const float4*)(Wx + (size_t)row * 1568 + 32 + q * 4);
    ushort4 r;
    r.x = f2b(v.x); r.y = f2b(v.y); r.z = f2b(v.z); r.w = f2b(v.w);
    *(ushort4*)(o + (size_t)row * 1536 + q * 4) = r;
}

// ---------------------------------------------------------------------------
// Depthwise causal conv (width 4) + bias + SiLU, 8 channels/thread, bf16.
// ---------------------------------------------------------------------------
__global__ __launch_bounds__(256) void conv_silu8(
    const unsigned short* __restrict__ xzb, const float* __restrict__ w,
    const float* __restrict__ cb, unsigned short* __restrict__ ub)
{
    const int i = blockIdx.x * 256 + threadIdx.x;    // over NROWS*192
    if (i >= NROWS * 192) return;
    const int g   = i % 192;
    const int row = i / 192;
    const int l   = row % SEQLEN;
    const int d0  = g * 8;

    short8 xr[4];
    #pragma unroll
    for (int k = 0; k < 4; ++k) {
        const int ll = l - 3 + k;
        if (ll >= 0)
            xr[k] = *(const short8*)&xzb[(size_t)(row - 3 + k) * 3072 + d0];
        else
            xr[k] = short8{0,0,0,0,0,0,0,0};
    }
    unsigned short o[8];
    #pragma unroll
    for (int e = 0; e < 8; ++e) {
        float4 we = *(const float4*)&w[(d0 + e) * 4];
        float a = cb[d0 + e];
        a = fmaf(b2f((unsigned short)xr[0][e]), we.x, a);
        a = fmaf(b2f((unsigned short)xr[1][e]), we.y, a);
        a = fmaf(b2f((unsigned short)xr[2][e]), we.z, a);
        a = fmaf(b2f((unsigned short)xr[3][e]), we.w, a);
        o[e] = f2b(a / (1.f + __expf(-a)));
    }
    *(short8*)&ub[(size_t)row * 1536 + d0] = *(short8*)o;
}

// ---------------------------------------------------------------------------
// Per-row softmax over B (16) + copy C (16) from compact xp32[row][32].
// ---------------------------------------------------------------------------
__global__ __launch_bounds__(256) void softmax_bc_kernel(
    const float* __restrict__ xp32, float* __restrict__ Bsm, float* __restrict__ Csm)
{
    const int row = blockIdx.x * 256 + threadIdx.x;
    if (row >= NROWS) return;
    const float* p = xp32 + (size_t)row * 32;
    float v[16];
    #pragma unroll
    for (int q = 0; q < 4; ++q) {
        float4 t = *(const float4*)(p + q * 4);
        v[q*4+0]=t.x; v[q*4+1]=t.y; v[q*4+2]=t.z; v[q*4+3]=t.w;
    }
    float mx = v[0];
    #pragma unroll
    for (int s = 1; s < 16; ++s) mx = fmaxf(mx, v[s]);
    float sum = 0.f;
    #pragma unroll
    for (int s = 0; s < 16; ++s) { v[s] = __expf(v[s] - mx); sum += v[s]; }
    const float inv = 1.f / sum;
    float* bo = Bsm + (size_t)row * 16;
    float* co = Csm + (size_t)row * 16;
    #pragma unroll
    for (int s = 0; s < 16; ++s) bo[s] = v[s] * inv;
    #pragma unroll
    for (int q = 0; q < 4; ++q)
        *(float4*)(co + q * 4) = *(const float4*)(p + 16 + q * 4);
}

// ---------------------------------------------------------------------------
// Scan phase A: per (b, chunk, d): chunk-final state (zero init) + dt-sum.
// delta is bf16 — A and C read identical values so the chunk decomposition
// identity stays exact.
// ---------------------------------------------------------------------------
__global__ __launch_bounds__(256) void scan_chunk_state(
    const unsigned short* __restrict__ deltab, const unsigned short* __restrict__ ub,
    const float* __restrict__ Bsm, const float* __restrict__ A_log,
    float* __restrict__ chunkS, float* __restrict__ dtsum)
{
    const int gid = blockIdx.x * 256 + threadIdx.x;   // (b*NCHUNK+c)*D_INNER+d
    const int d = gid % D_INNER;
    const int c = (gid / D_INNER) % NCHUNK;
    const int b = gid / (D_INNER * NCHUNK);

    float A2[16];
    #pragma unroll
    for (int q = 0; q < 4; ++q) {
        float4 t = *(const float4*)(A_log + d * 16 + q * 4);
        A2[q*4+0] = -__expf(t.x) * 1.44269504089f;
        A2[q*4+1] = -__expf(t.y) * 1.44269504089f;
        A2[q*4+2] = -__expf(t.z) * 1.44269504089f;
        A2[q*4+3] = -__expf(t.w) * 1.44269504089f;
    }
    float h[16];
    #pragma unroll
    for (int s = 0; s < 16; ++s) h[s] = 0.f;
    float dts = 0.f;

    const int t0 = c * LCHUNK;
    for (int t = t0; t < t0 + LCHUNK; ++t) {
        const size_t rowoff = (size_t)b * SEQLEN + t;
        const float dt = b2f(deltab[rowoff * D_INNER + d]);
        const float uu = b2f(ub[rowoff * D_INNER + d]);
        const float du = dt * uu;
        dts += dt;
        const float4* Bp = (const float4*)(Bsm + rowoff * 16);
        float Bv[16];
        #pragma unroll
        for (int q = 0; q < 4; ++q) {
            float4 tb = Bp[q];
            Bv[q*4+0]=tb.x; Bv[q*4+1]=tb.y; Bv[q*4+2]=tb.z; Bv[q*4+3]=tb.w;
        }
        #pragma unroll
        for (int s = 0; s < 16; ++s) {
            const float dA = exp2f(dt * A2[s]);
            h[s] = fmaf(dA, h[s], du * Bv[s]);
        }
    }
    float* S = chunkS + (size_t)gid * 16;
    #pragma unroll
    for (int q = 0; q < 4; ++q)
        *(float4*)(S + q * 4) = make_float4(h[q*4+0], h[q*4+1], h[q*4+2], h[q*4+3]);
    dtsum[gid] = dts;
}

// ---------------------------------------------------------------------------
// Scan phase B: inter-chunk scan; chunkS becomes chunk-INITIAL states.
// ---------------------------------------------------------------------------
__global__ __launch_bounds__(256) void scan_chunk_scan(
    const float* __restrict__ A_log, const float* __restrict__ dtsum,
    float* __restrict__ chunkS)
{
    const int gid = blockIdx.x * 256 + threadIdx.x;   // (b*D_INNER+d)*16+s
    if (gid >= BATCH * D_INNER * 16) return;
    const int s = gid % 16;
    const int d = (gid / 16) % D_INNER;
    const int b = gid / (16 * D_INNER);
    const float A2 = -__expf(A_log[d * 16 + s]) * 1.44269504089f;
    float hprev = 0.f;
    for (int c = 0; c < NCHUNK; ++c) {
        const size_t cidx = ((size_t)(b * NCHUNK + c) * D_INNER + d);
        const float P  = exp2f(A2 * dtsum[cidx]);
        const size_t idx = cidx * 16 + s;
        const float Sc = chunkS[idx];
        chunkS[idx] = hprev;
        hprev = fmaf(P, hprev, Sc);
    }
}

// ---------------------------------------------------------------------------
// Scan phase C: re-run chunks from initial states, y = (C.h) * silu(z), bf16.
// ---------------------------------------------------------------------------
__global__ __launch_bounds__(256) void scan_output(
    const unsigned short* __restrict__ deltab, const unsigned short* __restrict__ ub,
    const float* __restrict__ Bsm, const float* __restrict__ Csm,
    const float* __restrict__ A_log, const float* __restrict__ chunkS,
    const unsigned short* __restrict__ xzb, unsigned short* __restrict__ yb)
{
    const int gid = blockIdx.x * 256 + threadIdx.x;
    const int d = gid % D_INNER;
    const int c = (gid / D_INNER) % NCHUNK;
    const int b = gid / (D_INNER * NCHUNK);

    float A2[16];
    #pragma unroll
    for (int q = 0; q < 4; ++q) {
        float4 t = *(const float4*)(A_log + d * 16 + q * 4);
        A2[q*4+0] = -__expf(t.x) * 1.44269504089f;
        A2[q*4+1] = -__expf(t.y) * 1.44269504089f;
        A2[q*4+2] = -__expf(t.z) * 1.44269504089f;
        A2[q*4+3] = -__expf(t.w) * 1.44269504089f;
    }
    float h[16];
    const float* S = chunkS + (size_t)gid * 16;
    #pragma unroll
    for (int q = 0; q < 4; ++q) {
        float4 t = *(const float4*)(S + q * 4);
        h[q*4+0]=t.x; h[q*4+1]=t.y; h[q*4+2]=t.z; h[q*4+3]=t.w;
    }

    const int t0 = c * LCHUNK;
    for (int t = t0; t < t0 + LCHUNK; ++t) {
        const size_t rowoff = (size_t)b * SEQLEN + t;
        const float dt = b2f(deltab[rowoff * D_INNER + d]);
        const float uu = b2f(ub[rowoff * D_INNER + d]);
        const float du = dt * uu;
        const float4* Bp = (const float4*)(Bsm + rowoff * 16);
        const float4* Cp = (const float4*)(Csm + rowoff * 16);
        float Bv[16], Cv[16];
        #pragma unroll
        for (int q = 0; q < 4; ++q) {
            float4 tb = Bp[q], tc = Cp[q];
            Bv[q*4+0]=tb.x; Bv[q*4+1]=tb.y; Bv[q*4+2]=tb.z; Bv[q*4+3]=tb.w;
            Cv[q*4+0]=tc.x; Cv[q*4+1]=tc.y; Cv[q*4+2]=tc.z; Cv[q*4+3]=tc.w;
        }
        float yv = 0.f;
        #pragma unroll
        for (int s = 0; s < 16; ++s) {
            const float dA = exp2f(dt * A2[s]);
            h[s] = fmaf(dA, h[s], du * Bv[s]);
            yv = fmaf(Cv[s], h[s], yv);
        }
        const float z = b2f(xzb[rowoff * (2 * D_INNER) + D_INNER + d]);
        const float sz = z / (1.f + __expf(-z));
        yb[rowoff * D_INNER + d] = f2b(yv * sz);
    }
}

// ---------------------------------------------------------------------------
extern "C" void kernel_launch(void* const* d_in, const int* in_sizes, int n_in,
                              void* d_out, int out_size, void* d_ws, size_t ws_size,
                              hipStream_t stream)
{
    const float* hs     = (const float*)d_in[0];
    const float* W_in   = (const float*)d_in[1];
    const float* conv_w = (const float*)d_in[2];
    const float* conv_b = (const float*)d_in[3];
    const float* W_x    = (const float*)d_in[4];
    const float* W_dt   = (const float*)d_in[5];
    const float* b_dt   = (const float*)d_in[6];
    const float* A_log  = (const float*)d_in[7];
    const float* W_out  = (const float*)d_in[9];
    float* out = (float*)d_out;

    // workspace layout (256B aligned)
    char* w = (char*)d_ws;
    auto alloc = [&](size_t bytes) { char* p = w; w += (bytes + 255) & ~(size_t)255; return p; };
    float*          xp32   = (float*)alloc((size_t)NROWS * 32 * 4);
    unsigned short* deltab = (unsigned short*)alloc((size_t)NROWS * 1536 * 2);
    float*          Bsm    = (float*)alloc((size_t)NROWS * 16 * 4);
    float*          Csm    = (float*)alloc((size_t)NROWS * 16 * 4);
    float*          chunkS = (float*)alloc((size_t)BATCH * NCHUNK * D_INNER * 16 * 4);
    float*          dtsum  = (float*)alloc((size_t)BATCH * NCHUNK * D_INNER * 4);
    unsigned short* xzb    = (unsigned short*)alloc((size_t)NROWS * 3072 * 2);
    unsigned short* ub     = (unsigned short*)alloc((size_t)NROWS * 1536 * 2);
    unsigned short* yb     = (unsigned short*)alloc((size_t)NROWS * 1536 * 2);
    unsigned short* hsb    = (unsigned short*)alloc((size_t)NROWS * 768 * 2);
    unsigned short* Wt_in  = (unsigned short*)alloc((size_t)3072 * 768 * 2);
    unsigned short* Wt_x   = (unsigned short*)alloc((size_t)1792 * 1536 * 2);
    unsigned short* Wt_dt  = (unsigned short*)alloc((size_t)1536 * 1536 * 2);
    unsigned short* Wt_out = (unsigned short*)alloc((size_t)768 * 1536 * 2);
    unsigned short* wxb    = (unsigned short*)alloc((size_t)1536 * 1536 * 2);

    const dim3 blk(256);

    // 0) weight transposes + converts
    transpose_bf16<<<dim3(3072/32, 768/32),  blk, 0, stream>>>(W_in,  Wt_in,  768,  3072);
    transpose_bf16<<<dim3(1792/32, 1536/32), blk, 0, stream>>>(W_x,   Wt_x,   1536, 1568);
    transpose_bf16<<<dim3(1536/32, 1536/32), blk, 0, stream>>>(W_dt,  Wt_dt,  1536, 1536);
    transpose_bf16<<<dim3(768/32,  1536/32), blk, 0, stream>>>(W_out, Wt_out, 1536, 768);
    f32_to_bf16<<<(NROWS*768/4 + 255)/256, blk, 0, stream>>>(hs, hsb, NROWS*768/4);
    wx32_to_bf16<<<(1536*384 + 255)/256, blk, 0, stream>>>(W_x, wxb);

    // 0b) W_comb^T = (W_x[:,32:] @ W_dt)^T spliced into Wt_x rows 32..1567:
    //     [M=1536, N=1536, K=1536; grid 12*12=144, %8==0; fallback mapping]
    gemm_p2<0,1><<<dim3(144), blk, 0, stream>>>(
        Wt_dt, 1536, wxb, 1536, Wt_x + (size_t)32 * 1536, 1536, nullptr,
        1536, 1536, nullptr, 12);

    // 1) xz = hs @ W_in  (bf16 out)  [K=768, NT=24; grid 24*64=1536, %8==0]
    gemm_p2<0,1><<<dim3(1536), blk, 0, stream>>>(
        hsb, 768, Wt_in, 768, xzb, 3072, nullptr, 3072, 768, nullptr, 24);

    // 2) u = silu(conv(x) + cb)
    conv_silu8<<<(NROWS*192)/256, blk, 0, stream>>>(xzb, conv_w, conv_b, ub);

    // 3) fused xp+delta GEMM: u @ [W_x[:,:32] | W_comb]:
    //    cols<32 -> xp32 f32;  cols>=32 -> delta = softplus(acc+b_dt) bf16
    //    [K=1536, NT=48; grid 14*64=896, %8==0]
    gemm_p2<3,0><<<dim3(896), blk, 0, stream>>>(
        ub, 1536, Wt_x, 1536, deltab, 1536, xp32, 1568, 1536, b_dt, 14);

    // 4) Bsm = softmax(xp32[:, :16]), Csm = xp32[:, 16:32]
    softmax_bc_kernel<<<NROWS/256, blk, 0, stream>>>(xp32, Bsm, Csm);

    // 5-7) chunked selective scan (NCHUNK=128: 1536 blocks for A/C)
    scan_chunk_state<<<(BATCH*NCHUNK*D_INNER)/256, blk, 0, stream>>>(
        deltab, ub, Bsm, A_log, chunkS, dtsum);
    scan_chunk_scan<<<(BATCH*D_INNER*16 + 255)/256, blk, 0, stream>>>(
        A_log, dtsum, chunkS);
    scan_output<<<(BATCH*NCHUNK*D_INNER)/256, blk, 0, stream>>>(
        deltab, ub, Bsm, Csm, A_log, chunkS, xzb, yb);

    // 8) out = y @ W_out  (f32 out)  [K=1536, NT=48; grid 6*64=384, %8==0]
    gemm_p2<0,0><<<dim3(384), blk, 0, stream>>>(
        yb, 1536, Wt_out, 1536, out, 768, nullptr, 768, 1536, nullptr, 6);
}

// Round 14
// 442.654 us; speedup vs baseline: 1.1301x; 1.0000x over previous
//
#include <hip/hip_runtime.h>
#include <hip/hip_bf16.h>
#include <math.h>

#define D_MODEL 768
#define D_STATE 16
#define D_CONVW 4
#define D_INNER 1536
#define BATCH   2
#define SEQLEN  4096
#define NROWS   (BATCH*SEQLEN)       // 8192
#define NCHUNK  128                  // scan TLP: 1536 blocks for phases A/C
#define LCHUNK  (SEQLEN/NCHUNK)      // 32

typedef __attribute__((ext_vector_type(8))) short short8;
typedef __attribute__((ext_vector_type(4))) float floatx4;

__device__ inline unsigned short f2b(float x) {
    unsigned u = __float_as_uint(x);
    return (unsigned short)((u + 0x7fffu + ((u >> 16) & 1u)) >> 16);   // RNE
}
__device__ inline float b2f(unsigned short b) {
    return __uint_as_float(((unsigned)b) << 16);
}

#define GLDS(gp, lp) __builtin_amdgcn_global_load_lds( \
    (const __attribute__((address_space(1))) void*)(gp), \
    (__attribute__((address_space(3))) void*)(lp), 16, 0, 0)

// ---------------------------------------------------------------------------
// r14: 256x128 (MxN) 8-wave variant of the proven r11/r13 schedule.
// Per-wave code IDENTICAL to gemm_p2 (64x64 quadrant, 4x4 16x16x32 frags,
// swizzled ds_read, 2-buffer + 2-barrier + counted vmcnt STEP).  Only block
// geometry changes: 2x MFMA work per barrier interval, staged bytes/FLOP
// -25%.  A: 2 GLDS/thread (q*128 rows keeps the granule involution:
// q*128>>1 === 0 mod 4), B: 1 GLDS -> counted vmcnt(3).
// LDS 48 KiB -> 3 blocks/CU x 8 waves = 24 waves/CU.
// EPI: 0 plain (OUTBF16 sel), 3 fused xp+delta (gn<32 -> f32 C2,
//      else softplus(acc+bias[gn-32]) -> bf16 Cv).  NT=K/32 even.
// Grid 1D = nbx*(M/256), %8==0.
// ---------------------------------------------------------------------------
template<int EPI, int OUTBF16>
__global__ __launch_bounds__(512, 4) void gemm_w8(
    const unsigned short* __restrict__ A, int lda,
    const unsigned short* __restrict__ Bt, int ldb,
    void* __restrict__ Cv, int ldc, float* __restrict__ C2,
    int N, int K, const float* __restrict__ bias, int nbx)
{
    __shared__ unsigned short As0[256*32], As1[256*32];
    __shared__ unsigned short Bs0[128*32], Bs1[128*32];

    const int nwg = gridDim.x;
    const int cpx = nwg >> 3;
    const int wg  = blockIdx.x;
    const int xcd = wg & 7, local = wg >> 3;
    int bmi, bni;
    if ((cpx % nbx == 0) && ((nbx & 1) == 0)) {
        const int R   = cpx / nbx;
        const int p   = local / (2 * R);
        const int idx = local % (2 * R);
        bmi = xcd * R + (idx >> 1);
        bni = p * 2 + (idx & 1);
    } else {
        const int swz = xcd * cpx + local;
        bmi = swz / nbx;
        bni = swz % nbx;
    }
    const int bm = bmi * 256;
    const int bn = bni * 128;

    const int tid  = threadIdx.x;          // 0..511
    const int lane = tid & 63;
    const int wave = tid >> 6;             // 0..7
    const int wm   = (wave >> 1) * 64;     // 0,64,128,192
    const int wn   = (wave & 1) * 64;      // 0,64
    const int l15  = lane & 15;
    const int lg   = lane >> 4;

    const int sr    = tid >> 2;                              // 0..127
    const int sg    = ((tid & 3) ^ ((tid >> 3) & 3)) * 8;    // swizzled src granule
    const int lbase = (tid & ~63) * 16;                      // wave-uniform LDS base

    floatx4 acc[4][4] = {};

    auto stagePair = [&](unsigned short (&SA)[256*32],
                         unsigned short (&SB)[128*32], int kt) {
        #pragma unroll
        for (int q = 0; q < 2; ++q) {
            const unsigned short* ga = A + (size_t)(bm + q * 128 + sr) * lda + kt + sg;
            GLDS(ga, (char*)SA + q * 8192 + lbase);
        }
        const unsigned short* gb = Bt + (size_t)(bn + sr) * ldb + kt + sg;
        GLDS(gb, (char*)SB + lbase);
    };

    auto compute = [&](const unsigned short (&CA)[256*32],
                       const unsigned short (&CB)[128*32]) {
        short8 af[4], bfv[4];
        #pragma unroll
        for (int i = 0; i < 4; ++i) {
            const int tr = wm + i * 16 + l15;
            const int ge = lg ^ ((tr >> 1) & 3);
            af[i] = *(const short8*)((const char*)CA + tr * 64 + ge * 16);
        }
        #pragma unroll
        for (int j = 0; j < 4; ++j) {
            const int tr = wn + j * 16 + l15;
            const int ge = lg ^ ((tr >> 1) & 3);
            bfv[j] = *(const short8*)((const char*)CB + tr * 64 + ge * 16);
        }
        #pragma unroll
        for (int i = 0; i < 4; ++i)
            #pragma unroll
            for (int j = 0; j < 4; ++j)
                acc[i][j] = __builtin_amdgcn_mfma_f32_16x16x32_bf16(
                    af[i], bfv[j], acc[i][j], 0, 0, 0);
    };

    const int NT = K >> 5;                 // K/32, even

    stagePair(As0, Bs0, 0);                // prologue: tile 0 -> buf0

    #define STEP(SA, SB, CA, CB, T)                                          \
    {                                                                        \
        const int t_ = (T);                                                  \
        if (t_ + 1 < NT) {                                                   \
            stagePair(SA, SB, (t_ + 1) * 32);                                \
            asm volatile("s_waitcnt vmcnt(3)" ::: "memory");                 \
        } else {                                                             \
            asm volatile("s_waitcnt vmcnt(0)" ::: "memory");                 \
        }                                                                    \
        __builtin_amdgcn_sched_barrier(0);                                   \
        __builtin_amdgcn_s_barrier();                                        \
        __builtin_amdgcn_sched_barrier(0);                                   \
        compute(CA, CB);                                                     \
        __builtin_amdgcn_sched_barrier(0);                                   \
        __builtin_amdgcn_s_barrier();                                        \
        __builtin_amdgcn_sched_barrier(0);                                   \
    }

    for (int t = 0; t < NT; t += 2) {
        STEP(As1, Bs1, As0, Bs0, t);
        STEP(As0, Bs0, As1, Bs1, t + 1);
    }
    #undef STEP

    // C/D layout: col = lane&15, row = (lane>>4)*4 + reg  (m89-verified)
    #pragma unroll
    for (int i = 0; i < 4; ++i) {
        #pragma unroll
        for (int r = 0; r < 4; ++r) {
            const int gm = bm + wm + i * 16 + lg * 4 + r;
            #pragma unroll
            for (int j = 0; j < 4; ++j) {
                const int gn = bn + wn + j * 16 + l15;
                float v = acc[i][j][r];
                if (EPI == 3) {
                    if (gn < 32) {
                        C2[(size_t)gm * 32 + gn] = v;
                    } else if (gn < N) {
                        v += bias[gn - 32];
                        v = (v > 20.f) ? v : log1pf(__expf(v));
                        ((unsigned short*)Cv)[(size_t)gm * 1536 + gn - 32] = f2b(v);
                    }
                } else {
                    if (gn < N) {
                        if (OUTBF16)
                            ((unsigned short*)Cv)[(size_t)gm * ldc + gn] = f2b(v);
                        else
                            ((float*)Cv)[(size_t)gm * ldc + gn] = v;
                    }
                }
            }
        }
    }
}

// ---------------------------------------------------------------------------
// 128x128 bf16 MFMA GEMM — r11/r13 proven structure (for small grids:
// Wcomb 144 blocks, out-proj 384 blocks).
// ---------------------------------------------------------------------------
template<int EPI, int OUTBF16>
__global__ __launch_bounds__(256, 4) void gemm_p2(
    const unsigned short* __restrict__ A, int lda,
    const unsigned short* __restrict__ Bt, int ldb,
    void* __restrict__ Cv, int ldc, float* __restrict__ C2,
    int N, int K, const float* __restrict__ bias, int nbx)
{
    __shared__ unsigned short As0[128*32], As1[128*32];
    __shared__ unsigned short Bs0[128*32], Bs1[128*32];

    const int nwg = gridDim.x;
    const int cpx = nwg >> 3;
    const int wg  = blockIdx.x;
    const int xcd = wg & 7, local = wg >> 3;
    int bmi, bni;
    if ((cpx % nbx == 0) && ((nbx & 1) == 0)) {
        const int R   = cpx / nbx;
        const int p   = local / (2 * R);
        const int idx = local % (2 * R);
        bmi = xcd * R + (idx >> 1);
        bni = p * 2 + (idx & 1);
    } else {
        const int swz = xcd * cpx + local;
        bmi = swz / nbx;
        bni = swz % nbx;
    }
    const int bm = bmi * 128;
    const int bn = bni * 128;

    const int tid  = threadIdx.x;
    const int lane = tid & 63;
    const int wave = tid >> 6;
    const int wm   = (wave >> 1) * 64;
    const int wn   = (wave & 1) * 64;
    const int l15  = lane & 15;
    const int lg   = lane >> 4;

    const int sr    = tid >> 2;
    const int sg    = ((tid & 3) ^ ((tid >> 3) & 3)) * 8;
    const int lbase = (tid & ~63) * 16;

    floatx4 acc[4][4] = {};

    auto stagePair = [&](unsigned short (&SA)[128*32],
                         unsigned short (&SB)[128*32], int kt) {
        #pragma unroll
        for (int p = 0; p < 2; ++p) {
            const unsigned short* ga = A + (size_t)(bm + p * 64 + sr) * lda + kt + sg;
            GLDS(ga, (char*)SA + p * 4096 + lbase);
        }
        #pragma unroll
        for (int p = 0; p < 2; ++p) {
            const unsigned short* gb = Bt + (size_t)(bn + p * 64 + sr) * ldb + kt + sg;
            GLDS(gb, (char*)SB + p * 4096 + lbase);
        }
    };

    auto compute = [&](const unsigned short (&CA)[128*32],
                       const unsigned short (&CB)[128*32]) {
        short8 af[4], bfv[4];
        #pragma unroll
        for (int i = 0; i < 4; ++i) {
            const int tr = wm + i * 16 + l15;
            const int ge = lg ^ ((tr >> 1) & 3);
            af[i] = *(const short8*)((const char*)CA + tr * 64 + ge * 16);
        }
        #pragma unroll
        for (int j = 0; j < 4; ++j) {
            const int tr = wn + j * 16 + l15;
            const int ge = lg ^ ((tr >> 1) & 3);
            bfv[j] = *(const short8*)((const char*)CB + tr * 64 + ge * 16);
        }
        #pragma unroll
        for (int i = 0; i < 4; ++i)
            #pragma unroll
            for (int j = 0; j < 4; ++j)
                acc[i][j] = __builtin_amdgcn_mfma_f32_16x16x32_bf16(
                    af[i], bfv[j], acc[i][j], 0, 0, 0);
    };

    const int NT = K >> 5;                 // K/32, even

    stagePair(As0, Bs0, 0);

    #define STEP(SA, SB, CA, CB, T)                                          \
    {                                                                        \
        const int t_ = (T);                                                  \
        if (t_ + 1 < NT) {                                                   \
            stagePair(SA, SB, (t_ + 1) * 32);                                \
            asm volatile("s_waitcnt vmcnt(4)" ::: "memory");                 \
        } else {                                                             \
            asm volatile("s_waitcnt vmcnt(0)" ::: "memory");                 \
        }                                                                    \
        __builtin_amdgcn_sched_barrier(0);                                   \
        __builtin_amdgcn_s_barrier();                                        \
        __builtin_amdgcn_sched_barrier(0);                                   \
        compute(CA, CB);                                                     \
        __builtin_amdgcn_sched_barrier(0);                                   \
        __builtin_amdgcn_s_barrier();                                        \
        __builtin_amdgcn_sched_barrier(0);                                   \
    }

    for (int t = 0; t < NT; t += 2) {
        STEP(As1, Bs1, As0, Bs0, t);
        STEP(As0, Bs0, As1, Bs1, t + 1);
    }
    #undef STEP

    #pragma unroll
    for (int i = 0; i < 4; ++i) {
        #pragma unroll
        for (int r = 0; r < 4; ++r) {
            const int gm = bm + wm + i * 16 + lg * 4 + r;
            #pragma unroll
            for (int j = 0; j < 4; ++j) {
                const int gn = bn + wn + j * 16 + l15;
                float v = acc[i][j][r];
                if (gn < N) {
                    if (OUTBF16)
                        ((unsigned short*)Cv)[(size_t)gm * ldc + gn] = f2b(v);
                    else
                        ((float*)Cv)[(size_t)gm * ldc + gn] = v;
                }
            }
        }
    }
}

// ---------------------------------------------------------------------------
// W[K][N] f32 -> Wt[N_pad][K] bf16 (pad rows zeroed).  32x32 LDS transpose.
// ---------------------------------------------------------------------------
__global__ __launch_bounds__(256) void transpose_bf16(
    const float* __restrict__ W, unsigned short* __restrict__ Wt, int K, int N)
{
    __shared__ float t[32][33];
    const int nt = blockIdx.x * 32, kt = blockIdx.y * 32;
    const int tx = threadIdx.x & 31, ty = threadIdx.x >> 5;
    #pragma unroll
    for (int r = 0; r < 4; ++r) {
        const int k = ty + r * 8;
        const int n = nt + tx;
        float v = 0.f;
        if (n < N) v = W[(size_t)(kt + k) * N + n];
        t[k][tx] = v;
    }
    __syncthreads();
    #pragma unroll
    for (int r = 0; r < 4; ++r) {
        const int nl = ty + r * 8;
        Wt[(size_t)(nt + nl) * K + kt + tx] = f2b(t[tx][nl]);
    }
}

__global__ __launch_bounds__(256) void f32_to_bf16(
    const float* __restrict__ in, unsigned short* __restrict__ o, int n4)
{
    const int i = blockIdx.x * 256 + threadIdx.x;
    if (i >= n4) return;
    float4 v = ((const float4*)in)[i];
    ushort4 r;
    r.x = f2b(v.x); r.y = f2b(v.y); r.z = f2b(v.z); r.w = f2b(v.w);
    ((ushort4*)o)[i] = r;
}

// W_x[:, 32:] f32 (stride 1568) -> wxb[1536][1536] bf16
__global__ __launch_bounds__(256) void wx32_to_bf16(
    const float* __restrict__ Wx, unsigned short* __restrict__ o)
{
    const int i = blockIdx.x * 256 + threadIdx.x;   // over 1536*384
    if (i >= 1536 * 384) return;
    const int row = i / 384, q = i % 384;
    float4 v = *(const float4*)(Wx + (size_t)row * 1568 + 32 + q * 4);
    ushort4 r;
    r.x = f2b(v.x); r.y = f2b(v.y); r.z = f2b(v.z); r.w = f2b(v.w);
    *(ushort4*)(o + (size_t)row * 1536 + q * 4) = r;
}

// ---------------------------------------------------------------------------
// Depthwise causal conv (width 4) + bias + SiLU, 8 channels/thread, bf16.
// ---------------------------------------------------------------------------
__global__ __launch_bounds__(256) void conv_silu8(
    const unsigned short* __restrict__ xzb, const float* __restrict__ w,
    const float* __restrict__ cb, unsigned short* __restrict__ ub)
{
    const int i = blockIdx.x * 256 + threadIdx.x;    // over NROWS*192
    if (i >= NROWS * 192) return;
    const int g   = i % 192;
    const int row = i / 192;
    const int l   = row % SEQLEN;
    const int d0  = g * 8;

    short8 xr[4];
    #pragma unroll
    for (int k = 0; k < 4; ++k) {
        const int ll = l - 3 + k;
        if (ll >= 0)
            xr[k] = *(const short8*)&xzb[(size_t)(row - 3 + k) * 3072 + d0];
        else
            xr[k] = short8{0,0,0,0,0,0,0,0};
    }
    unsigned short o[8];
    #pragma unroll
    for (int e = 0; e < 8; ++e) {
        float4 we = *(const float4*)&w[(d0 + e) * 4];
        float a = cb[d0 + e];
        a = fmaf(b2f((unsigned short)xr[0][e]), we.x, a);
        a = fmaf(b2f((unsigned short)xr[1][e]), we.y, a);
        a = fmaf(b2f((unsigned short)xr[2][e]), we.z, a);
        a = fmaf(b2f((unsigned short)xr[3][e]), we.w, a);
        o[e] = f2b(a / (1.f + __expf(-a)));
    }
    *(short8*)&ub[(size_t)row * 1536 + d0] = *(short8*)o;
}

// ---------------------------------------------------------------------------
// Per-row softmax over B (16) + copy C (16) from compact xp32[row][32].
// ---------------------------------------------------------------------------
__global__ __launch_bounds__(256) void softmax_bc_kernel(
    const float* __restrict__ xp32, float* __restrict__ Bsm, float* __restrict__ Csm)
{
    const int row = blockIdx.x * 256 + threadIdx.x;
    if (row >= NROWS) return;
    const float* p = xp32 + (size_t)row * 32;
    float v[16];
    #pragma unroll
    for (int q = 0; q < 4; ++q) {
        float4 t = *(const float4*)(p + q * 4);
        v[q*4+0]=t.x; v[q*4+1]=t.y; v[q*4+2]=t.z; v[q*4+3]=t.w;
    }
    float mx = v[0];
    #pragma unroll
    for (int s = 1; s < 16; ++s) mx = fmaxf(mx, v[s]);
    float sum = 0.f;
    #pragma unroll
    for (int s = 0; s < 16; ++s) { v[s] = __expf(v[s] - mx); sum += v[s]; }
    const float inv = 1.f / sum;
    float* bo = Bsm + (size_t)row * 16;
    float* co = Csm + (size_t)row * 16;
    #pragma unroll
    for (int s = 0; s < 16; ++s) bo[s] = v[s] * inv;
    #pragma unroll
    for (int q = 0; q < 4; ++q)
        *(float4*)(co + q * 4) = *(const float4*)(p + 16 + q * 4);
}

// ---------------------------------------------------------------------------
// Scan phase A: per (b, chunk, d): chunk-final state (zero init) + dt-sum.
// ---------------------------------------------------------------------------
__global__ __launch_bounds__(256) void scan_chunk_state(
    const unsigned short* __restrict__ deltab, const unsigned short* __restrict__ ub,
    const float* __restrict__ Bsm, const float* __restrict__ A_log,
    float* __restrict__ chunkS, float* __restrict__ dtsum)
{
    const int gid = blockIdx.x * 256 + threadIdx.x;   // (b*NCHUNK+c)*D_INNER+d
    const int d = gid % D_INNER;
    const int c = (gid / D_INNER) % NCHUNK;
    const int b = gid / (D_INNER * NCHUNK);

    float A2[16];
    #pragma unroll
    for (int q = 0; q < 4; ++q) {
        float4 t = *(const float4*)(A_log + d * 16 + q * 4);
        A2[q*4+0] = -__expf(t.x) * 1.44269504089f;
        A2[q*4+1] = -__expf(t.y) * 1.44269504089f;
        A2[q*4+2] = -__expf(t.z) * 1.44269504089f;
        A2[q*4+3] = -__expf(t.w) * 1.44269504089f;
    }
    float h[16];
    #pragma unroll
    for (int s = 0; s < 16; ++s) h[s] = 0.f;
    float dts = 0.f;

    const int t0 = c * LCHUNK;
    for (int t = t0; t < t0 + LCHUNK; ++t) {
        const size_t rowoff = (size_t)b * SEQLEN + t;
        const float dt = b2f(deltab[rowoff * D_INNER + d]);
        const float uu = b2f(ub[rowoff * D_INNER + d]);
        const float du = dt * uu;
        dts += dt;
        const float4* Bp = (const float4*)(Bsm + rowoff * 16);
        float Bv[16];
        #pragma unroll
        for (int q = 0; q < 4; ++q) {
            float4 tb = Bp[q];
            Bv[q*4+0]=tb.x; Bv[q*4+1]=tb.y; Bv[q*4+2]=tb.z; Bv[q*4+3]=tb.w;
        }
        #pragma unroll
        for (int s = 0; s < 16; ++s) {
            const float dA = exp2f(dt * A2[s]);
            h[s] = fmaf(dA, h[s], du * Bv[s]);
        }
    }
    float* S = chunkS + (size_t)gid * 16;
    #pragma unroll
    for (int q = 0; q < 4; ++q)
        *(float4*)(S + q * 4) = make_float4(h[q*4+0], h[q*4+1], h[q*4+2], h[q*4+3]);
    dtsum[gid] = dts;
}

// ---------------------------------------------------------------------------
// Scan phase B: inter-chunk scan; chunkS becomes chunk-INITIAL states.
// ---------------------------------------------------------------------------
__global__ __launch_bounds__(256) void scan_chunk_scan(
    const float* __restrict__ A_log, const float* __restrict__ dtsum,
    float* __restrict__ chunkS)
{
    const int gid = blockIdx.x * 256 + threadIdx.x;   // (b*D_INNER+d)*16+s
    if (gid >= BATCH * D_INNER * 16) return;
    const int s = gid % 16;
    const int d = (gid / 16) % D_INNER;
    const int b = gid / (16 * D_INNER);
    const float A2 = -__expf(A_log[d * 16 + s]) * 1.44269504089f;
    float hprev = 0.f;
    for (int c = 0; c < NCHUNK; ++c) {
        const size_t cidx = ((size_t)(b * NCHUNK + c) * D_INNER + d);
        const float P  = exp2f(A2 * dtsum[cidx]);
        const size_t idx = cidx * 16 + s;
        const float Sc = chunkS[idx];
        chunkS[idx] = hprev;
        hprev = fmaf(P, hprev, Sc);
    }
}

// ---------------------------------------------------------------------------
// Scan phase C: re-run chunks from initial states, y = (C.h) * silu(z), bf16.
// ---------------------------------------------------------------------------
__global__ __launch_bounds__(256) void scan_output(
    const unsigned short* __restrict__ deltab, const unsigned short* __restrict__ ub,
    const float* __restrict__ Bsm, const float* __restrict__ Csm,
    const float* __restrict__ A_log, const float* __restrict__ chunkS,
    const unsigned short* __restrict__ xzb, unsigned short* __restrict__ yb)
{
    const int gid = blockIdx.x * 256 + threadIdx.x;
    const int d = gid % D_INNER;
    const int c = (gid / D_INNER) % NCHUNK;
    const int b = gid / (D_INNER * NCHUNK);

    float A2[16];
    #pragma unroll
    for (int q = 0; q < 4; ++q) {
        float4 t = *(const float4*)(A_log + d * 16 + q * 4);
        A2[q*4+0] = -__expf(t.x) * 1.44269504089f;
        A2[q*4+1] = -__expf(t.y) * 1.44269504089f;
        A2[q*4+2] = -__expf(t.z) * 1.44269504089f;
        A2[q*4+3] = -__expf(t.w) * 1.44269504089f;
    }
    float h[16];
    const float* S = chunkS + (size_t)gid * 16;
    #pragma unroll
    for (int q = 0; q < 4; ++q) {
        float4 t = *(const float4*)(S + q * 4);
        h[q*4+0]=t.x; h[q*4+1]=t.y; h[q*4+2]=t.z; h[q*4+3]=t.w;
    }

    const int t0 = c * LCHUNK;
    for (int t = t0; t < t0 + LCHUNK; ++t) {
        const size_t rowoff = (size_t)b * SEQLEN + t;
        const float dt = b2f(deltab[rowoff * D_INNER + d]);
        const float uu = b2f(ub[rowoff * D_INNER + d]);
        const float du = dt * uu;
        const float4* Bp = (const float4*)(Bsm + rowoff * 16);
        const float4* Cp = (const float4*)(Csm + rowoff * 16);
        float Bv[16], Cv[16];
        #pragma unroll
        for (int q = 0; q < 4; ++q) {
            float4 tb = Bp[q], tc = Cp[q];
            Bv[q*4+0]=tb.x; Bv[q*4+1]=tb.y; Bv[q*4+2]=tb.z; Bv[q*4+3]=tb.w;
            Cv[q*4+0]=tc.x; Cv[q*4+1]=tc.y; Cv[q*4+2]=tc.z; Cv[q*4+3]=tc.w;
        }
        float yv = 0.f;
        #pragma unroll
        for (int s = 0; s < 16; ++s) {
            const float dA = exp2f(dt * A2[s]);
            h[s] = fmaf(dA, h[s], du * Bv[s]);
            yv = fmaf(Cv[s], h[s], yv);
        }
        const float z = b2f(xzb[rowoff * (2 * D_INNER) + D_INNER + d]);
        const float sz = z / (1.f + __expf(-z));
        yb[rowoff * D_INNER + d] = f2b(yv * sz);
    }
}

// ---------------------------------------------------------------------------
extern "C" void kernel_launch(void* const* d_in, const int* in_sizes, int n_in,
                              void* d_out, int out_size, void* d_ws, size_t ws_size,
                              hipStream_t stream)
{
    const float* hs     = (const float*)d_in[0];
    const float* W_in   = (const float*)d_in[1];
    const float* conv_w = (const float*)d_in[2];
    const float* conv_b = (const float*)d_in[3];
    const float* W_x    = (const float*)d_in[4];
    const float* W_dt   = (const float*)d_in[5];
    const float* b_dt   = (const float*)d_in[6];
    const float* A_log  = (const float*)d_in[7];
    const float* W_out  = (const float*)d_in[9];
    float* out = (float*)d_out;

    // workspace layout (256B aligned)
    char* w = (char*)d_ws;
    auto alloc = [&](size_t bytes) { char* p = w; w += (bytes + 255) & ~(size_t)255; return p; };
    float*          xp32   = (float*)alloc((size_t)NROWS * 32 * 4);
    unsigned short* deltab = (unsigned short*)alloc((size_t)NROWS * 1536 * 2);
    float*          Bsm    = (float*)alloc((size_t)NROWS * 16 * 4);
    float*          Csm    = (float*)alloc((size_t)NROWS * 16 * 4);
    float*          chunkS = (float*)alloc((size_t)BATCH * NCHUNK * D_INNER * 16 * 4);
    float*          dtsum  = (float*)alloc((size_t)BATCH * NCHUNK * D_INNER * 4);
    unsigned short* xzb    = (unsigned short*)alloc((size_t)NROWS * 3072 * 2);
    unsigned short* ub     = (unsigned short*)alloc((size_t)NROWS * 1536 * 2);
    unsigned short* yb     = (unsigned short*)alloc((size_t)NROWS * 1536 * 2);
    unsigned short* hsb    = (unsigned short*)alloc((size_t)NROWS * 768 * 2);
    unsigned short* Wt_in  = (unsigned short*)alloc((size_t)3072 * 768 * 2);
    unsigned short* Wt_x   = (unsigned short*)alloc((size_t)1792 * 1536 * 2);
    unsigned short* Wt_dt  = (unsigned short*)alloc((size_t)1536 * 1536 * 2);
    unsigned short* Wt_out = (unsigned short*)alloc((size_t)768 * 1536 * 2);
    unsigned short* wxb    = (unsigned short*)alloc((size_t)1536 * 1536 * 2);

    const dim3 blk(256);

    // 0) weight transposes + converts
    transpose_bf16<<<dim3(3072/32, 768/32),  blk, 0, stream>>>(W_in,  Wt_in,  768,  3072);
    transpose_bf16<<<dim3(1792/32, 1536/32), blk, 0, stream>>>(W_x,   Wt_x,   1536, 1568);
    transpose_bf16<<<dim3(1536/32, 1536/32), blk, 0, stream>>>(W_dt,  Wt_dt,  1536, 1536);
    transpose_bf16<<<dim3(768/32,  1536/32), blk, 0, stream>>>(W_out, Wt_out, 1536, 768);
    f32_to_bf16<<<(NROWS*768/4 + 255)/256, blk, 0, stream>>>(hs, hsb, NROWS*768/4);
    wx32_to_bf16<<<(1536*384 + 255)/256, blk, 0, stream>>>(W_x, wxb);

    // 0b) W_comb^T = (W_x[:,32:] @ W_dt)^T spliced into Wt_x rows 32..1567:
    //     [M=1536, N=1536, K=1536; grid 12*12=144, %8==0; 128^2 kernel]
    gemm_p2<0,1><<<dim3(144), blk, 0, stream>>>(
        Wt_dt, 1536, wxb, 1536, Wt_x + (size_t)32 * 1536, 1536, nullptr,
        1536, 1536, nullptr, 12);

    // 1) xz = hs @ W_in  (bf16 out)  [256x128 8-wave; K=768; grid 32*24=768]
    gemm_w8<0,1><<<dim3(768), dim3(512), 0, stream>>>(
        hsb, 768, Wt_in, 768, xzb, 3072, nullptr, 3072, 768, nullptr, 24);

    // 2) u = silu(conv(x) + cb)
    conv_silu8<<<(NROWS*192)/256, blk, 0, stream>>>(xzb, conv_w, conv_b, ub);

    // 3) fused xp+delta GEMM: u @ [W_x[:,:32] | W_comb]
    //    [256x128 8-wave; K=1536; grid 32*13=416, %8==0]
    gemm_w8<3,0><<<dim3(416), dim3(512), 0, stream>>>(
        ub, 1536, Wt_x, 1536, deltab, 1536, xp32, 1568, 1536, b_dt, 13);

    // 4) Bsm = softmax(xp32[:, :16]), Csm = xp32[:, 16:32]
    softmax_bc_kernel<<<NROWS/256, blk, 0, stream>>>(xp32, Bsm, Csm);

    // 5-7) chunked selective scan (NCHUNK=128: 1536 blocks for A/C)
    scan_chunk_state<<<(BATCH*NCHUNK*D_INNER)/256, blk, 0, stream>>>(
        deltab, ub, Bsm, A_log, chunkS, dtsum);
    scan_chunk_scan<<<(BATCH*D_INNER*16 + 255)/256, blk, 0, stream>>>(
        A_log, dtsum, chunkS);
    scan_output<<<(BATCH*NCHUNK*D_INNER)/256, blk, 0, stream>>>(
        deltab, ub, Bsm, Csm, A_log, chunkS, xzb, yb);

    // 8) out = y @ W_out  (f32 out)  [128^2; grid 6*64=384, %8==0]
    gemm_p2<0,0><<<dim3(384), blk, 0, stream>>>(
        yb, 1536, Wt_out, 1536, out, 768, nullptr, 768, 1536, nullptr, 6);
}